// Round 7
// baseline (239.046 us; speedup 1.0000x reference)
//
#include <hip/hip_runtime.h>
#include <hip/hip_bf16.h>

// Problem constants: B=8, d=16, H=W=512, K=8
#define BB 8
#define DD 16
#define KK 8
#define NN (512 * 512)
#define G4 (NN / 4)               // 65536 float4-groups per (b,d) plane

constexpr int BPB = 256;          // blocks per batch (k_var) -> grid = 2048
constexpr int T   = 256;          // threads per block (4 waves)
constexpr int WV  = 4;            // waves per block

// ws layout (floats):
#define WS_SUMS    0      // [B][K][D]  (atomics, zeroed)
#define WS_CNTS    1024   // [B][K]     (atomics, zeroed)
#define WS_VARSUMS 1088   // [B][K]     (atomics, zeroed)
#define WS_TOTAL   1152

// ---------------- Pass 1: per-(b,k) sums and counts -------------------------
// Plane-uniform waves: block e -> b = e&7 (XCD-pinned: batch's labels stay in
// one XCD's L2), d = (e>>3)&15, seg = e>>7. Every wave load is 1 KB fully
// contiguous (float4 data + int4 labels at the same group index); the owned
// dim d is block-uniform so only s[K]=8 accumulators are needed.
// Labels re-read once per d-plane: L2 hits after first touch (1 MB/batch).
__global__ __launch_bounds__(T, 8) void k_sums(const float* __restrict__ data,
                                               const int* __restrict__ labels,
                                               float* __restrict__ ws) {
    const int e    = blockIdx.x;
    const int b    = e & 7;            // XCD-pinned batch
    const int rem  = e >> 3;           // 0..255
    const int d    = rem & 15;         // dim plane
    const int sb   = rem >> 4;         // 0..15 segment-block within plane
    const int tid  = threadIdx.x;
    const int wv   = tid >> 6;
    const int lane = tid & 63;

    const float4* dpl = (const float4*)(data + ((size_t)b * DD + d) * NN);
    const int4*   lp4 = (const int4*)(labels + (size_t)b * NN);

    const int gbase = sb * 4096 + wv * 1024 + lane;  // 16 iters x 64 lanes

    float s[KK], c[KK];
#pragma unroll
    for (int k = 0; k < KK; ++k) { s[k] = 0.f; c[k] = 0.f; }

#pragma unroll 4
    for (int i = 0; i < 16; ++i) {
        const int g = gbase + i * 64;
        float4 x  = dpl[g];            // 1 KB contiguous per wave
        int4   lb = lp4[g];            // 1 KB contiguous per wave (L2-hot)
        int   labs[4] = {lb.x, lb.y, lb.z, lb.w};
        float xs[4]   = {x.x, x.y, x.z, x.w};
#pragma unroll
        for (int p = 0; p < 4; ++p) {
            const int   l = labs[p];
            const float a = xs[p];
#pragma unroll
            for (int k = 0; k < KK; ++k)
                s[k] += (l == k) ? a : 0.f;
        }
        if (d == 0) {                  // count each point exactly once
#pragma unroll
            for (int p = 0; p < 4; ++p) {
                const int l = labs[p];
#pragma unroll
                for (int k = 0; k < KK; ++k)
                    c[k] += (l == k) ? 1.f : 0.f;
            }
        }
    }

    // full 64-lane reduce
#pragma unroll
    for (int k = 0; k < KK; ++k) {
#pragma unroll
        for (int m = 1; m < 64; m <<= 1) s[k] += __shfl_xor(s[k], m, 64);
    }
    if (d == 0) {
#pragma unroll
        for (int k = 0; k < KK; ++k) {
#pragma unroll
            for (int m = 1; m < 64; m <<= 1) c[k] += __shfl_xor(c[k], m, 64);
        }
    }

    __shared__ float sred[WV][KK];
    __shared__ float cred[WV][KK];
    if (lane == 0) {
#pragma unroll
        for (int k = 0; k < KK; ++k) { sred[wv][k] = s[k]; cred[wv][k] = c[k]; }
    }
    __syncthreads();

    if (tid < KK) {
        float v = sred[0][tid] + sred[1][tid] + sred[2][tid] + sred[3][tid];
        atomicAdd(&ws[WS_SUMS + (b * KK + tid) * DD + d], v);
    } else if (d == 0 && tid >= 64 && tid < 64 + KK) {
        const int k = tid - 64;
        float v = cred[0][k] + cred[1][k] + cred[2][k] + cred[3][k];
        atomicAdd(&ws[WS_CNTS + b * KK + k], v);
    }
}

// ---------------- Pass 2: variance term (lane-owns-point, no shuffles) ------
__global__ __launch_bounds__(T, 8) void k_var(const float* __restrict__ data,
                                              const int* __restrict__ labels,
                                              float* __restrict__ ws) {
    const int b   = blockIdx.x / BPB;
    const int blk = blockIdx.x % BPB;
    const int tid = threadIdx.x;

    __shared__ float cs[KK * 17 + DD];   // centers, stride-17 padded (conflict-free)
    if (tid < KK * DD) {
        const int k = tid >> 4, d = tid & 15;
        cs[k * 17 + d] = ws[WS_SUMS + (b * KK + k) * DD + d] / ws[WS_CNTS + b * KK + k];
    }
    __syncthreads();

    const float4* dp4 = (const float4*)(data + (size_t)b * DD * NN);
    const int4*   lp4 = (const int4*)(labels + (size_t)b * NN);
    const int g = blk * T + tid;         // one float4-group (4 points) per thread

    int4 lb = lp4[g];
    int labs[4] = {lb.x, lb.y, lb.z, lb.w};
    float ss[4] = {0.f, 0.f, 0.f, 0.f};
#pragma unroll 4
    for (int d = 0; d < DD; ++d) {
        float4 x = dp4[(size_t)d * G4 + g];      // 1 KB contiguous per wave
        float xs[4] = {x.x, x.y, x.z, x.w};
#pragma unroll
        for (int p = 0; p < 4; ++p) {
            float c  = cs[labs[p] * 17 + d];     // broadcast / distinct banks
            float df = xs[p] - c;
            ss[p] = fmaf(df, df, ss[p]);
        }
    }

    float acc[KK];
#pragma unroll
    for (int k = 0; k < KK; ++k) acc[k] = 0.f;
#pragma unroll
    for (int p = 0; p < 4; ++p) {
        float e  = fmaxf(sqrtf(ss[p]) - 1.0f, 0.f);   // DELTA_VAR = 1
        float e2 = e * e;
#pragma unroll
        for (int k = 0; k < KK; ++k) acc[k] += (labs[p] == k) ? e2 : 0.f;
    }

    const int lane = tid & 63, wv = tid >> 6;
#pragma unroll
    for (int k = 0; k < KK; ++k) {
#pragma unroll
        for (int m = 1; m < 64; m <<= 1) acc[k] += __shfl_xor(acc[k], m, 64);
    }
    __shared__ float vred[WV][KK];
    if (lane == 0) {
#pragma unroll
        for (int k = 0; k < KK; ++k) vred[wv][k] = acc[k];
    }
    __syncthreads();
    if (tid < KK) {
        float v = 0.f;
#pragma unroll
        for (int q = 0; q < WV; ++q) v += vred[q][tid];
        atomicAdd(&ws[WS_VARSUMS + b * KK + tid], v);
    }
}

// ---------------- Final: centers + dist/reg/var combine ---------------------
__global__ void k_final(const float* __restrict__ ws, float* __restrict__ out) {
    const int t = threadIdx.x;           // 0..63 : b = t>>3, k = t&7
    const int b = t >> 3, k = t & 7;
    const float inv = 1.0f / ws[WS_CNTS + t];
    __shared__ float sc[BB * KK][DD];
    float cen[DD];
    float n2 = 0.f;
#pragma unroll
    for (int d = 0; d < DD; ++d) {
        float v = ws[WS_SUMS + t * DD + d] * inv;
        cen[d] = v;
        sc[t][d] = v;
        n2 = fmaf(v, v, n2);
    }
    __syncthreads();
    float rg = fmaxf(sqrtf(n2) - 4.0f, 0.f);   // delta_reg = sqrt(16) = 4
    rg *= rg;
    float rowcost = 0.f;
#pragma unroll
    for (int j = 0; j < KK; ++j) {
        float d2 = 0.f;
#pragma unroll
        for (int d = 0; d < DD; ++d) {
            float df = cen[d] - sc[b * KK + j][d];
            d2 = fmaf(df, df, d2);
        }
        float dm = sqrtf(d2) + ((j == k) ? 2.0f : 0.0f);   // eye*DELTA_DIST trick
        float h = fmaxf(2.0f - dm, 0.f);
        rowcost += h * h;
    }
    float var  = ws[WS_VARSUMS + t] * inv;
    float term = var / (float)KK + rowcost / 56.0f + rg / (float)KK;
#pragma unroll
    for (int m = 1; m < 64; m <<= 1) term += __shfl_xor(term, m, 64);
    if (t == 0) out[0] = term / (float)BB;
}

extern "C" void kernel_launch(void* const* d_in, const int* in_sizes, int n_in,
                              void* d_out, int out_size, void* d_ws, size_t ws_size,
                              hipStream_t stream) {
    const float* data   = (const float*)d_in[0];
    const int*   labels = (const int*)d_in[1];
    float*       ws     = (float*)d_ws;

    hipMemsetAsync(d_ws, 0, WS_TOTAL * sizeof(float), stream);
    k_sums<<<2048, T, 0, stream>>>(data, labels, ws);
    k_var<<<BB * BPB, T, 0, stream>>>(data, labels, ws);
    k_final<<<1, 64, 0, stream>>>(ws, (float*)d_out);
}